// Round 16
// baseline (236.351 us; speedup 1.0000x reference)
//
#include <hip/hip_runtime.h>

// NewSupConLoss: B=512, L=20, D=128. Full Gram N=10240, fused exp/rowsum.
// Round 16: R11 base (best: 6400 single-wave units, 64 rows x 256 cols,
// 16-col slices, af persistent 64 VGPR, swizzled fswz) + depth-2 staging
// (3x4KB LDS ring, vmcnt(8): loads issued 2 compute phases before use) +
// k_final folded into k_ws via completion counter (one fewer dispatch).

#define NB 512
#define NL 20
#define NROW (NB * NL)            // 10240
#define FBYTES (NROW * 256)       // 2,621,440
#define SCALE 4.5398160f          // sqrt(log2(e)/0.07); dot feeds exp2 directly
#define TEMP_INV 14.285714285714286f
#define WS_BLOCKS 2600

typedef float f32x4 __attribute__((ext_vector_type(4)));
typedef short short8 __attribute__((ext_vector_type(8)));
typedef unsigned short ushort4v __attribute__((ext_vector_type(4)));

static __device__ __forceinline__ unsigned short f2bf(float x) {
  unsigned int b = __float_as_uint(x);
  b += 0x7FFFu + ((b >> 16) & 1u);
  return (unsigned short)(b >> 16);
}

static __device__ __forceinline__ float fexp2(float x) {
#if __has_builtin(__builtin_amdgcn_exp2f)
  return __builtin_amdgcn_exp2f(x);
#else
  return exp2f(x);
#endif
}

// Blocks [0,1280): fp32 -> bf16 rows a=l*512+i, scaled, XOR-swizzled.
// Blocks [1280,1600): gp[c][grp][d] partial g-sums. Block 0 zeroes counter.
__global__ __launch_bounds__(256) void k_prep(const float* __restrict__ feat,
                                              const int* __restrict__ labels,
                                              unsigned char* __restrict__ fswz,
                                              float* __restrict__ gp,
                                              unsigned int* __restrict__ ctr) {
  const int b = blockIdx.x;
  if (b == 0 && threadIdx.x == 0) *ctr = 0u;
  if (b < 1280) {
    int t = b * 256 + threadIdx.x;   // [0, 327680)
    int q = t & 31;
    int a = t >> 5;
    int l = a >> 9;
    int i = a & 511;
    const float* src = feat + (size_t)i * (NL * 128) + l * 128 + q * 4;
    float4 v = *(const float4*)src;
    ushort4v u;
    u.x = f2bf(v.x * SCALE); u.y = f2bf(v.y * SCALE);
    u.z = f2bf(v.z * SCALE); u.w = f2bf(v.w * SCALE);
    int dst = a * 256 + ((q * 8) ^ ((a & 7) << 4));
    *(ushort4v*)(fswz + dst) = u;
  } else {
    __shared__ float part[2][128];
    const int idx = b - 1280;          // [0,320)
    const int c = idx >> 4, grp = idx & 15;
    const int d = threadIdx.x & 127, half = threadIdx.x >> 7;
    const int i0 = grp * 32 + half * 16;
    float s = 0.f;
#pragma unroll
    for (int k = 0; k < 16; ++k) {     // independent load pairs, latency-hidden
      int i = i0 + k;
      s += (float)labels[i * NL + c] * feat[(size_t)i * (NL * 128) + c * 128 + d];
    }
    part[half][d] = s;
    __syncthreads();
    if (half == 0) gp[(c * 16 + grp) * 128 + d] = part[0][d] + part[1][d];
  }
}

// Pr[c][h][sr][r] : partial row-sums of exp over 256 cols (class c, half h).
// Grid (320 = sr*2+h, 20 c), 64 threads (1 wave). Depth-2 staged, 3x4KB LDS.
__global__ __launch_bounds__(64) void k_gram(const unsigned char* __restrict__ fswz,
                                             float* __restrict__ Pr) {
  __shared__ unsigned char lds[12288];   // three wave-private 4KB slice buffers
  const int x = blockIdx.x;              // [0,320)
  const int h = x & 1, sr = x >> 1;      // col half, 64-row strip [sr*64,+64)
  const int c = blockIdx.y;              // class: cols [c*512 + h*256, +256)
  const int lane = threadIdx.x;          // 0..63
  const int fr = lane & 15, kg = lane >> 4;
  const int xr = (fr & 7) << 4;

  // ---- persistent A fragments: 16 x short8 = 64 VGPR ----
  short8 af[4][4];   // [kk][m]
#pragma unroll
  for (int kk = 0; kk < 4; ++kk)
#pragma unroll
    for (int m = 0; m < 4; ++m)
      af[kk][m] = *(const short8*)(fswz + (size_t)(sr * 64 + m * 16 + fr) * 256 +
                                   ((kk * 64 + kg * 16) ^ xr));

  const unsigned char* gB = fswz + ((size_t)c * 512 + h * 256) * 256 + lane * 16;
  auto stage = [&](int buf, int t) {     // slice t: 16 Gram-cols = 4KB
    const unsigned char* g = gB + t * 4096;
    unsigned char* lb = lds + buf * 4096 + lane * 16;
#pragma unroll
    for (int p = 0; p < 4; ++p)
      __builtin_amdgcn_global_load_lds(
          (const __attribute__((address_space(1))) unsigned int*)(g + p * 1024),
          (__attribute__((address_space(3))) unsigned int*)(lb + p * 1024), 16, 0, 0);
  };

  stage(0, 0);
  stage(1, 1);
  float esum[4][4] = {};   // [m][reg]
  int bi = 0;

  // diag (i==j) lives in half (d8>>2), slices [td0, td0+4), d8 = sr&7
  const int d8 = sr & 7;
  const bool diagh = ((d8 >> 2) == h);
  const int td0 = (d8 & 3) * 4;

  for (int t = 0; t < 16; ++t) {
    asm volatile("" ::: "memory");   // keep stage below prior ds_reads
    if (t < 14) {
      int nb = bi + 2; if (nb >= 3) nb -= 3;
      stage(nb, t + 2);
      asm volatile("s_waitcnt vmcnt(8)" ::: "memory");   // slice t resident
    } else if (t < 15) {
      asm volatile("s_waitcnt vmcnt(4)" ::: "memory");
    } else {
      asm volatile("s_waitcnt vmcnt(0)" ::: "memory");
    }

    const unsigned char* lb = lds + bi * 4096;
    f32x4 acc[4] = {};   // 64 rows x 16 cols
#pragma unroll
    for (int kk = 0; kk < 4; ++kk) {
      short8 bf = *(const short8*)(lb + fr * 256 + ((kk * 64 + kg * 16) ^ xr));
#pragma unroll
      for (int m = 0; m < 4; ++m)
        acc[m] = __builtin_amdgcn_mfma_f32_16x16x32_bf16(af[kk][m], bf, acc[m], 0, 0, 0);
    }

    // ---- epilogue: exp + accumulate; mask only on the 4 diag slices ----
    if (diagh && t >= td0 && t < td0 + 4) {
      const int mt = t - td0;
#pragma unroll
      for (int m = 0; m < 4; ++m)
#pragma unroll
        for (int reg = 0; reg < 4; ++reg) {
          float ex = fexp2(acc[m][reg]);
          if (m == mt && (kg * 4 + reg) == fr) ex = 0.f;
          esum[m][reg] += ex;
        }
    } else {
#pragma unroll
      for (int m = 0; m < 4; ++m)
#pragma unroll
        for (int reg = 0; reg < 4; ++reg)
          esum[m][reg] += fexp2(acc[m][reg]);
    }
    if (++bi == 3) bi = 0;
  }

  // ---- flush once: reduce over fr (16 cols) + plain stores ----
#pragma unroll
  for (int m = 0; m < 4; ++m)
#pragma unroll
    for (int reg = 0; reg < 4; ++reg) {
      float e = esum[m][reg];
      e += __shfl_xor(e, 1, 64); e += __shfl_xor(e, 2, 64);
      e += __shfl_xor(e, 4, 64); e += __shfl_xor(e, 8, 64);
      if (fr == 0)
        Pr[(((size_t)c * 2 + h) * 160 + sr) * 64 + m * 16 + kg * 4 + reg] = e;
    }
}

// Blocks [0,2560): wnum (wave per (c,i), folds 16 gp partials, coalesced).
// Blocks [2560,2600): Slog = log(sum of 40 Pr partials), coalesced.
// Last block to finish (completion counter) runs the final combine+mean.
__global__ __launch_bounds__(256) void k_ws(const float* __restrict__ Pr,
                                            const float* __restrict__ feat,
                                            const float* __restrict__ gp,
                                            const int* __restrict__ labels,
                                            float* __restrict__ Slog,
                                            float* __restrict__ wnum,
                                            unsigned int* __restrict__ ctr,
                                            float* __restrict__ out) {
  const int b = blockIdx.x;
  if (b < 2560) {
    const int lane = threadIdx.x & 63;
    const int p = b * 4 + (threadIdx.x >> 6);   // pair c*512+i
    const int c = p >> 9, i = p & 511;
    float2 f = *(const float2*)(feat + (size_t)i * (NL * 128) + c * 128 + lane * 2);
    float gx = 0.f, gy = 0.f;
#pragma unroll
    for (int q = 0; q < 16; ++q) {
      float2 g2 = *(const float2*)(gp + (c * 16 + q) * 128 + lane * 2);
      gx += g2.x; gy += g2.y;
    }
    float v = f.x * gx + f.y * gy;
#pragma unroll
    for (int sh = 1; sh < 64; sh <<= 1) v += __shfl_xor(v, sh, 64);
    if (lane == 0) wnum[p] = (v - 1.f) * TEMP_INV;   // self term f.f==1 removed
  } else {
    int idx = (b - 2560) * 256 + threadIdx.x;   // [0, 10240)
    int c = idx >> 9, i = idx & 511;
    float s = 0.f;
#pragma unroll
    for (int l2 = 0; l2 < NL; ++l2) {
      const float* p2 = Pr + (((size_t)c * 2) * 160 + l2 * 8 + (i >> 6)) * 64 + (i & 63);
      s += p2[0] + p2[160 * 64];
    }
    Slog[idx] = logf(s);
  }

  // ---- completion counter: last block performs the final combine ----
  __shared__ unsigned int done_s;
  __threadfence();
  __syncthreads();
  if (threadIdx.x == 0) done_s = atomicAdd(ctr, 1u);
  __syncthreads();
  if (done_s != WS_BLOCKS - 1) return;
  __threadfence();   // acquire: all other blocks' Slog/wnum visible

  __shared__ float cnt[NL];
  __shared__ float red[4];
  const int tid = threadIdx.x;
  if (tid < NL) cnt[tid] = 0.f;
  __syncthreads();
  int lab0[NL], lab1[NL];
#pragma unroll
  for (int cI = 0; cI < NL; ++cI) {
    lab0[cI] = labels[tid * NL + cI];
    lab1[cI] = labels[(tid + 256) * NL + cI];
  }
#pragma unroll
  for (int cI = 0; cI < NL; ++cI) {
    if (lab0[cI]) atomicAdd(&cnt[cI], 1.f);
    if (lab1[cI]) atomicAdd(&cnt[cI], 1.f);
  }
  __syncthreads();
  float vs = 0.f;
#pragma unroll
  for (int half = 0; half < 2; ++half) {
    const int i = tid + half * 256;
    float avg = 0.f, acc = 0.f;
#pragma unroll
    for (int cI = 0; cI < NL; ++cI) {
      int lv = half ? lab1[cI] : lab0[cI];
      if (lv) {
        float wgt = cnt[cI] - 1.f;
        avg += wgt;
        acc += wnum[cI * NB + i] - wgt * Slog[cI * NB + i];
      }
    }
    vs += acc / (avg == 0.f ? 1.f : avg);
  }
#pragma unroll
  for (int s = 1; s < 64; s <<= 1) vs += __shfl_xor(vs, s, 64);
  if ((tid & 63) == 0) red[tid >> 6] = vs;
  __syncthreads();
  if (tid == 0)
    out[0] = -((red[0] + red[1] + red[2] + red[3]) / (float)NB);
}

extern "C" void kernel_launch(void* const* d_in, const int* in_sizes, int n_in,
                              void* d_out, int out_size, void* d_ws, size_t ws_size,
                              hipStream_t stream) {
  const float* feat = (const float*)d_in[0];
  const int* labels = (const int*)d_in[1];
  float* out = (float*)d_out;
  unsigned char* ws = (unsigned char*)d_ws;
  unsigned char* fswz = ws;                          // 2,621,440 B (swizzled)
  float* Pr = (float*)(ws + FBYTES);                 // 20*2*160*64 f32 = 1.6 MB
  float* gp = Pr + 20 * 2 * 160 * 64;                // 320*128 f32
  float* Slog = gp + 320 * 128;                      // 10240 f32
  float* wnum = Slog + NROW;                         // 10240 f32
  unsigned int* ctr = (unsigned int*)(wnum + NROW);  // completion counter

  k_prep<<<1600, 256, 0, stream>>>(feat, labels, fswz, gp, ctr);
  dim3 grid(320, 20);
  k_gram<<<grid, 64, 0, stream>>>(fswz, Pr);
  k_ws<<<WS_BLOCKS, 256, 0, stream>>>(Pr, feat, gp, labels, Slog, wnum, ctr, out);
}

// Round 17
// 63.424 us; speedup vs baseline: 3.7265x; 3.7265x over previous
//
#include <hip/hip_runtime.h>

// NewSupConLoss: B=512, L=20, D=128. Full Gram N=10240, fused exp/rowsum.
// Round 17: R11 launch structure restored (4 dispatches; R16's fused-fence
// k_ws was a 200us disaster: per-block device fences serialize L2).
// Single change vs R11: k_gram depth-2 staging (3x4KB ring, vmcnt(8) waits
// for loads issued two compute phases earlier).

#define NB 512
#define NL 20
#define NROW (NB * NL)            // 10240
#define FBYTES (NROW * 256)       // 2,621,440
#define SCALE 4.5398160f          // sqrt(log2(e)/0.07); dot feeds exp2 directly
#define TEMP_INV 14.285714285714286f

typedef float f32x4 __attribute__((ext_vector_type(4)));
typedef short short8 __attribute__((ext_vector_type(8)));
typedef unsigned short ushort4v __attribute__((ext_vector_type(4)));

static __device__ __forceinline__ unsigned short f2bf(float x) {
  unsigned int b = __float_as_uint(x);
  b += 0x7FFFu + ((b >> 16) & 1u);
  return (unsigned short)(b >> 16);
}

static __device__ __forceinline__ float fexp2(float x) {
#if __has_builtin(__builtin_amdgcn_exp2f)
  return __builtin_amdgcn_exp2f(x);
#else
  return exp2f(x);
#endif
}

// Blocks [0,1280): fp32 -> bf16 rows a=l*512+i, scaled, XOR-swizzled.
// Blocks [1280,1600): gp[c][grp][d] partial g-sums (16 independent loads).
__global__ __launch_bounds__(256) void k_prep(const float* __restrict__ feat,
                                              const int* __restrict__ labels,
                                              unsigned char* __restrict__ fswz,
                                              float* __restrict__ gp) {
  const int b = blockIdx.x;
  if (b < 1280) {
    int t = b * 256 + threadIdx.x;   // [0, 327680)
    int q = t & 31;
    int a = t >> 5;
    int l = a >> 9;
    int i = a & 511;
    const float* src = feat + (size_t)i * (NL * 128) + l * 128 + q * 4;
    float4 v = *(const float4*)src;
    ushort4v u;
    u.x = f2bf(v.x * SCALE); u.y = f2bf(v.y * SCALE);
    u.z = f2bf(v.z * SCALE); u.w = f2bf(v.w * SCALE);
    int dst = a * 256 + ((q * 8) ^ ((a & 7) << 4));
    *(ushort4v*)(fswz + dst) = u;
  } else {
    __shared__ float part[2][128];
    const int idx = b - 1280;          // [0,320)
    const int c = idx >> 4, grp = idx & 15;
    const int d = threadIdx.x & 127, half = threadIdx.x >> 7;
    const int i0 = grp * 32 + half * 16;
    float s = 0.f;
#pragma unroll
    for (int k = 0; k < 16; ++k) {     // independent load pairs, latency-hidden
      int i = i0 + k;
      s += (float)labels[i * NL + c] * feat[(size_t)i * (NL * 128) + c * 128 + d];
    }
    part[half][d] = s;
    __syncthreads();
    if (half == 0) gp[(c * 16 + grp) * 128 + d] = part[0][d] + part[1][d];
  }
}

// Pr[c][h][sr][r] : partial row-sums of exp over 256 cols (class c, half h).
// Grid (320 = sr*2+h, 20 c), 64 threads (1 wave). Depth-2 staged, 3x4KB LDS.
__global__ __launch_bounds__(64) void k_gram(const unsigned char* __restrict__ fswz,
                                             float* __restrict__ Pr) {
  __shared__ unsigned char lds[12288];   // three wave-private 4KB slice buffers
  const int x = blockIdx.x;              // [0,320)
  const int h = x & 1, sr = x >> 1;      // col half, 64-row strip [sr*64,+64)
  const int c = blockIdx.y;              // class: cols [c*512 + h*256, +256)
  const int lane = threadIdx.x;          // 0..63
  const int fr = lane & 15, kg = lane >> 4;
  const int xr = (fr & 7) << 4;

  // ---- persistent A fragments: 16 x short8 = 64 VGPR ----
  short8 af[4][4];   // [kk][m]
#pragma unroll
  for (int kk = 0; kk < 4; ++kk)
#pragma unroll
    for (int m = 0; m < 4; ++m)
      af[kk][m] = *(const short8*)(fswz + (size_t)(sr * 64 + m * 16 + fr) * 256 +
                                   ((kk * 64 + kg * 16) ^ xr));

  const unsigned char* gB = fswz + ((size_t)c * 512 + h * 256) * 256 + lane * 16;
  auto stage = [&](int buf, int t) {     // slice t: 16 Gram-cols = 4KB
    const unsigned char* g = gB + t * 4096;
    unsigned char* lb = lds + buf * 4096 + lane * 16;
#pragma unroll
    for (int p = 0; p < 4; ++p)
      __builtin_amdgcn_global_load_lds(
          (const __attribute__((address_space(1))) unsigned int*)(g + p * 1024),
          (__attribute__((address_space(3))) unsigned int*)(lb + p * 1024), 16, 0, 0);
  };

  stage(0, 0);
  stage(1, 1);
  float esum[4][4] = {};   // [m][reg]
  int bi = 0;

  // diag (i==j) lives in half (d8>>2), slices [td0, td0+4), d8 = sr&7
  const int d8 = sr & 7;
  const bool diagh = ((d8 >> 2) == h);
  const int td0 = (d8 & 3) * 4;

  for (int t = 0; t < 16; ++t) {
    asm volatile("" ::: "memory");   // keep stage below prior ds_reads
    if (t < 14) {
      int nb = bi + 2; if (nb >= 3) nb -= 3;
      stage(nb, t + 2);
      asm volatile("s_waitcnt vmcnt(8)" ::: "memory");   // slice t resident
    } else if (t < 15) {
      asm volatile("s_waitcnt vmcnt(4)" ::: "memory");
    } else {
      asm volatile("s_waitcnt vmcnt(0)" ::: "memory");
    }

    const unsigned char* lb = lds + bi * 4096;
    f32x4 acc[4] = {};   // 64 rows x 16 cols
#pragma unroll
    for (int kk = 0; kk < 4; ++kk) {
      short8 bf = *(const short8*)(lb + fr * 256 + ((kk * 64 + kg * 16) ^ xr));
#pragma unroll
      for (int m = 0; m < 4; ++m)
        acc[m] = __builtin_amdgcn_mfma_f32_16x16x32_bf16(af[kk][m], bf, acc[m], 0, 0, 0);
    }

    // ---- epilogue: exp + accumulate; mask only on the 4 diag slices ----
    if (diagh && t >= td0 && t < td0 + 4) {
      const int mt = t - td0;
#pragma unroll
      for (int m = 0; m < 4; ++m)
#pragma unroll
        for (int reg = 0; reg < 4; ++reg) {
          float ex = fexp2(acc[m][reg]);
          if (m == mt && (kg * 4 + reg) == fr) ex = 0.f;
          esum[m][reg] += ex;
        }
    } else {
#pragma unroll
      for (int m = 0; m < 4; ++m)
#pragma unroll
        for (int reg = 0; reg < 4; ++reg)
          esum[m][reg] += fexp2(acc[m][reg]);
    }
    if (++bi == 3) bi = 0;
  }

  // ---- flush once: reduce over fr (16 cols) + plain stores ----
#pragma unroll
  for (int m = 0; m < 4; ++m)
#pragma unroll
    for (int reg = 0; reg < 4; ++reg) {
      float e = esum[m][reg];
      e += __shfl_xor(e, 1, 64); e += __shfl_xor(e, 2, 64);
      e += __shfl_xor(e, 4, 64); e += __shfl_xor(e, 8, 64);
      if (fr == 0)
        Pr[(((size_t)c * 2 + h) * 160 + sr) * 64 + m * 16 + kg * 4 + reg] = e;
    }
}

// Blocks [0,2560): wnum (wave per (c,i), folds 16 gp partials, coalesced).
// Blocks [2560,2600): Slog = log(sum of 40 Pr partials), coalesced.
__global__ __launch_bounds__(256) void k_ws(const float* __restrict__ Pr,
                                            const float* __restrict__ feat,
                                            const float* __restrict__ gp,
                                            float* __restrict__ Slog,
                                            float* __restrict__ wnum) {
  const int b = blockIdx.x;
  if (b < 2560) {
    const int lane = threadIdx.x & 63;
    const int p = b * 4 + (threadIdx.x >> 6);   // pair c*512+i
    const int c = p >> 9, i = p & 511;
    float2 f = *(const float2*)(feat + (size_t)i * (NL * 128) + c * 128 + lane * 2);
    float gx = 0.f, gy = 0.f;
#pragma unroll
    for (int q = 0; q < 16; ++q) {
      float2 g2 = *(const float2*)(gp + (c * 16 + q) * 128 + lane * 2);
      gx += g2.x; gy += g2.y;
    }
    float v = f.x * gx + f.y * gy;
#pragma unroll
    for (int sh = 1; sh < 64; sh <<= 1) v += __shfl_xor(v, sh, 64);
    if (lane == 0) wnum[p] = (v - 1.f) * TEMP_INV;   // self term f.f==1 removed
  } else {
    int idx = (b - 2560) * 256 + threadIdx.x;   // [0, 10240)
    int c = idx >> 9, i = idx & 511;
    float s = 0.f;
#pragma unroll
    for (int l2 = 0; l2 < NL; ++l2) {
      const float* p2 = Pr + (((size_t)c * 2) * 160 + l2 * 8 + (i >> 6)) * 64 + (i & 63);
      s += p2[0] + p2[160 * 64];
    }
    Slog[idx] = logf(s);
  }
}

// Per-anchor combine + mean. One block, 512 threads.
__global__ __launch_bounds__(512) void k_final(const float* __restrict__ Slog,
                                               const float* __restrict__ wnum,
                                               const int* __restrict__ labels,
                                               float* __restrict__ out) {
  __shared__ float cnt[NL];
  __shared__ float red[8];
  const int i = threadIdx.x;
  if (i < NL) cnt[i] = 0.f;
  __syncthreads();
  int lab[NL];
#pragma unroll
  for (int cI = 0; cI < NL; ++cI) lab[cI] = labels[i * NL + cI];
#pragma unroll
  for (int cI = 0; cI < NL; ++cI)
    if (lab[cI]) atomicAdd(&cnt[cI], 1.f);
  __syncthreads();
  float avg = 0.f, acc = 0.f;
#pragma unroll
  for (int cI = 0; cI < NL; ++cI) {
    if (lab[cI]) {
      float wgt = cnt[cI] - 1.f;
      avg += wgt;
      acc += wnum[cI * NB + i] - wgt * Slog[cI * NB + i];
    }
  }
  float v = acc / (avg == 0.f ? 1.f : avg);
#pragma unroll
  for (int s = 1; s < 64; s <<= 1) v += __shfl_xor(v, s, 64);
  if ((i & 63) == 0) red[i >> 6] = v;
  __syncthreads();
  if (i == 0) {
    float tot = 0.f;
#pragma unroll
    for (int k = 0; k < 8; ++k) tot += red[k];
    out[0] = -(tot / (float)NB);
  }
}

extern "C" void kernel_launch(void* const* d_in, const int* in_sizes, int n_in,
                              void* d_out, int out_size, void* d_ws, size_t ws_size,
                              hipStream_t stream) {
  const float* feat = (const float*)d_in[0];
  const int* labels = (const int*)d_in[1];
  float* out = (float*)d_out;
  unsigned char* ws = (unsigned char*)d_ws;
  unsigned char* fswz = ws;                          // 2,621,440 B (swizzled)
  float* Pr = (float*)(ws + FBYTES);                 // 20*2*160*64 f32 = 1.6 MB
  float* gp = Pr + 20 * 2 * 160 * 64;                // 320*128 f32
  float* Slog = gp + 320 * 128;                      // 10240 f32
  float* wnum = Slog + NROW;                         // 10240 f32

  k_prep<<<1600, 256, 0, stream>>>(feat, labels, fswz, gp);
  dim3 grid(320, 20);
  k_gram<<<grid, 64, 0, stream>>>(fswz, Pr);
  k_ws<<<2600, 256, 0, stream>>>(Pr, feat, gp, Slog, wnum);
  k_final<<<1, 512, 0, stream>>>(Slog, wnum, labels, out);
}

// Round 18
// 53.525 us; speedup vs baseline: 4.4157x; 1.1849x over previous
//
#include <hip/hip_runtime.h>
#include <hip/hip_fp8.h>

// NewSupConLoss: B=512, L=20, D=128. Full Gram N=10240, fused exp/rowsum.
// Round 18: R11 structure exactly (6400 single-wave units, 64 rows x 256
// cols, 16-col slices, depth-1 staging), but FP8 e4m3 operands: halves all
// staged bytes (410->205MB) to attack the ~35 GB/s/CU staging ceiling the
// last 5 rounds plateaued on. Numerator stays fp32-exact via gp path.

#define NB 512
#define NL 20
#define NROW (NB * NL)            // 10240
#define F8BYTES (NROW * 128)      // 1,310,720
#define SCALE 4.5398160f          // sqrt(log2(e)/0.07); dot feeds exp2 directly
#define TEMP_INV 14.285714285714286f

typedef float f32x4 __attribute__((ext_vector_type(4)));

static __device__ __forceinline__ unsigned char f2fp8(float x) {
  __hip_fp8_e4m3 q(x);
  return (unsigned char)q.__x;
}

static __device__ __forceinline__ float fexp2(float x) {
#if __has_builtin(__builtin_amdgcn_exp2f)
  return __builtin_amdgcn_exp2f(x);
#else
  return exp2f(x);
#endif
}

// Blocks [0,640): fp32 -> fp8 rows a=l*512+i, scaled, 8B-chunk XOR-swizzled.
// Blocks [640,960): gp[c][grp][d] partial g-sums (16 independent loads).
__global__ __launch_bounds__(256) void k_prep(const float* __restrict__ feat,
                                              const int* __restrict__ labels,
                                              unsigned char* __restrict__ f8,
                                              float* __restrict__ gp) {
  const int b = blockIdx.x;
  if (b < 640) {
    int t = b * 256 + threadIdx.x;   // [0, 163840)
    int q = t & 15;                  // 8-elem chunk within row
    int a = t >> 4;                  // row 0..10239
    int l = a >> 9;
    int i = a & 511;
    const float* src = feat + (size_t)i * (NL * 128) + l * 128 + q * 8;
    float4 v0 = *(const float4*)src;
    float4 v1 = *(const float4*)(src + 4);
    unsigned long long u = 0;
    u |= (unsigned long long)f2fp8(v0.x * SCALE);
    u |= (unsigned long long)f2fp8(v0.y * SCALE) << 8;
    u |= (unsigned long long)f2fp8(v0.z * SCALE) << 16;
    u |= (unsigned long long)f2fp8(v0.w * SCALE) << 24;
    u |= (unsigned long long)f2fp8(v1.x * SCALE) << 32;
    u |= (unsigned long long)f2fp8(v1.y * SCALE) << 40;
    u |= (unsigned long long)f2fp8(v1.z * SCALE) << 48;
    u |= (unsigned long long)f2fp8(v1.w * SCALE) << 56;
    *(unsigned long long*)(f8 + (size_t)a * 128 + ((q ^ (a & 7)) << 3)) = u;
  } else {
    __shared__ float part[2][128];
    const int idx = b - 640;           // [0,320)
    const int c = idx >> 4, grp = idx & 15;
    const int d = threadIdx.x & 127, half = threadIdx.x >> 7;
    const int i0 = grp * 32 + half * 16;
    float s = 0.f;
#pragma unroll
    for (int k = 0; k < 16; ++k) {     // independent load pairs, latency-hidden
      int i = i0 + k;
      s += (float)labels[i * NL + c] * feat[(size_t)i * (NL * 128) + c * 128 + d];
    }
    part[half][d] = s;
    __syncthreads();
    if (half == 0) gp[(c * 16 + grp) * 128 + d] = part[0][d] + part[1][d];
  }
}

// Pr[c][h][sr][r] : partial row-sums of exp over 256 cols (class c, half h).
// Grid (320 = sr*2+h, 20 c), 64 threads (1 wave). Depth-1, 2x2KB LDS.
__global__ __launch_bounds__(64) void k_gram(const unsigned char* __restrict__ f8,
                                             float* __restrict__ Pr) {
  __shared__ unsigned char lds[4096];    // two wave-private 2KB slice buffers
  const int x = blockIdx.x;              // [0,320)
  const int h = x & 1, sr = x >> 1;      // col half, 64-row strip [sr*64,+64)
  const int c = blockIdx.y;              // class: cols [c*512 + h*256, +256)
  const int lane = threadIdx.x;          // 0..63
  const int fr = lane & 15, kg = lane >> 4;
  const int x8 = (fr & 7) << 3;

  // ---- persistent A fragments: 16 x long = 32 VGPR ----
  long af[4][4];   // [kk][m]
#pragma unroll
  for (int kk = 0; kk < 4; ++kk)
#pragma unroll
    for (int m = 0; m < 4; ++m)
      af[kk][m] = *(const long*)(f8 + (size_t)(sr * 64 + m * 16 + fr) * 128 +
                                 ((kk * 32 + kg * 8) ^ x8));

  const unsigned char* gB = f8 + ((size_t)c * 512 + h * 256) * 128 + lane * 16;
  auto stage = [&](int buf, int t) {     // slice t: 16 Gram-cols = 2KB
    const unsigned char* g = gB + t * 2048;
    unsigned char* lb = lds + buf * 2048 + lane * 16;
    __builtin_amdgcn_global_load_lds(
        (const __attribute__((address_space(1))) unsigned int*)g,
        (__attribute__((address_space(3))) unsigned int*)lb, 16, 0, 0);
    __builtin_amdgcn_global_load_lds(
        (const __attribute__((address_space(1))) unsigned int*)(g + 1024),
        (__attribute__((address_space(3))) unsigned int*)(lb + 1024), 16, 0, 0);
  };

  stage(0, 0);
  float esum[4][4] = {};   // [m][reg]

  // diag (i==j) lives in half (d8>>2), slices [td0, td0+4), d8 = sr&7
  const int d8 = sr & 7;
  const bool diagh = ((d8 >> 2) == h);
  const int td0 = (d8 & 3) * 4;

  for (int t = 0; t < 16; ++t) {
    asm volatile("" ::: "memory");   // keep stage below prior ds_reads
    if (t < 15) {
      stage((t + 1) & 1, t + 1);
      asm volatile("s_waitcnt vmcnt(2)" ::: "memory");   // slice t resident
    } else {
      asm volatile("s_waitcnt vmcnt(0)" ::: "memory");
    }

    const unsigned char* lb = lds + (t & 1) * 2048;
    f32x4 acc[4] = {};   // 64 rows x 16 cols
#pragma unroll
    for (int kk = 0; kk < 4; ++kk) {
      long bf = *(const long*)(lb + fr * 128 + ((kk * 32 + kg * 8) ^ x8));
#pragma unroll
      for (int m = 0; m < 4; ++m)
        acc[m] = __builtin_amdgcn_mfma_f32_16x16x32_fp8_fp8(af[kk][m], bf, acc[m], 0, 0, 0);
    }

    // ---- epilogue: exp + accumulate; mask only on the 4 diag slices ----
    if (diagh && t >= td0 && t < td0 + 4) {
      const int mt = t - td0;
#pragma unroll
      for (int m = 0; m < 4; ++m)
#pragma unroll
        for (int reg = 0; reg < 4; ++reg) {
          float ex = fexp2(acc[m][reg]);
          if (m == mt && (kg * 4 + reg) == fr) ex = 0.f;
          esum[m][reg] += ex;
        }
    } else {
#pragma unroll
      for (int m = 0; m < 4; ++m)
#pragma unroll
        for (int reg = 0; reg < 4; ++reg)
          esum[m][reg] += fexp2(acc[m][reg]);
    }
  }

  // ---- flush once: reduce over fr (16 cols) + plain stores ----
#pragma unroll
  for (int m = 0; m < 4; ++m)
#pragma unroll
    for (int reg = 0; reg < 4; ++reg) {
      float e = esum[m][reg];
      e += __shfl_xor(e, 1, 64); e += __shfl_xor(e, 2, 64);
      e += __shfl_xor(e, 4, 64); e += __shfl_xor(e, 8, 64);
      if (fr == 0)
        Pr[(((size_t)c * 2 + h) * 160 + sr) * 64 + m * 16 + kg * 4 + reg] = e;
    }
}

// Blocks [0,2560): wnum (wave per (c,i), folds 16 gp partials, coalesced).
// Blocks [2560,2600): Slog = log(sum of 40 Pr partials), coalesced.
__global__ __launch_bounds__(256) void k_ws(const float* __restrict__ Pr,
                                            const float* __restrict__ feat,
                                            const float* __restrict__ gp,
                                            float* __restrict__ Slog,
                                            float* __restrict__ wnum) {
  const int b = blockIdx.x;
  if (b < 2560) {
    const int lane = threadIdx.x & 63;
    const int p = b * 4 + (threadIdx.x >> 6);   // pair c*512+i
    const int c = p >> 9, i = p & 511;
    float2 f = *(const float2*)(feat + (size_t)i * (NL * 128) + c * 128 + lane * 2);
    float gx = 0.f, gy = 0.f;
#pragma unroll
    for (int q = 0; q < 16; ++q) {
      float2 g2 = *(const float2*)(gp + (c * 16 + q) * 128 + lane * 2);
      gx += g2.x; gy += g2.y;
    }
    float v = f.x * gx + f.y * gy;
#pragma unroll
    for (int sh = 1; sh < 64; sh <<= 1) v += __shfl_xor(v, sh, 64);
    if (lane == 0) wnum[p] = (v - 1.f) * TEMP_INV;   // self term f.f==1 removed
  } else {
    int idx = (b - 2560) * 256 + threadIdx.x;   // [0, 10240)
    int c = idx >> 9, i = idx & 511;
    float s = 0.f;
#pragma unroll
    for (int l2 = 0; l2 < NL; ++l2) {
      const float* p2 = Pr + (((size_t)c * 2) * 160 + l2 * 8 + (i >> 6)) * 64 + (i & 63);
      s += p2[0] + p2[160 * 64];
    }
    Slog[idx] = logf(s);
  }
}

// Per-anchor combine + mean. One block, 512 threads.
__global__ __launch_bounds__(512) void k_final(const float* __restrict__ Slog,
                                               const float* __restrict__ wnum,
                                               const int* __restrict__ labels,
                                               float* __restrict__ out) {
  __shared__ float cnt[NL];
  __shared__ float red[8];
  const int i = threadIdx.x;
  if (i < NL) cnt[i] = 0.f;
  __syncthreads();
  int lab[NL];
#pragma unroll
  for (int cI = 0; cI < NL; ++cI) lab[cI] = labels[i * NL + cI];
#pragma unroll
  for (int cI = 0; cI < NL; ++cI)
    if (lab[cI]) atomicAdd(&cnt[cI], 1.f);
  __syncthreads();
  float avg = 0.f, acc = 0.f;
#pragma unroll
  for (int cI = 0; cI < NL; ++cI) {
    if (lab[cI]) {
      float wgt = cnt[cI] - 1.f;
      avg += wgt;
      acc += wnum[cI * NB + i] - wgt * Slog[cI * NB + i];
    }
  }
  float v = acc / (avg == 0.f ? 1.f : avg);
#pragma unroll
  for (int s = 1; s < 64; s <<= 1) v += __shfl_xor(v, s, 64);
  if ((i & 63) == 0) red[i >> 6] = v;
  __syncthreads();
  if (i == 0) {
    float tot = 0.f;
#pragma unroll
    for (int k = 0; k < 8; ++k) tot += red[k];
    out[0] = -(tot / (float)NB);
  }
}

extern "C" void kernel_launch(void* const* d_in, const int* in_sizes, int n_in,
                              void* d_out, int out_size, void* d_ws, size_t ws_size,
                              hipStream_t stream) {
  const float* feat = (const float*)d_in[0];
  const int* labels = (const int*)d_in[1];
  float* out = (float*)d_out;
  unsigned char* ws = (unsigned char*)d_ws;
  unsigned char* f8 = ws;                            // 1,310,720 B (fp8 swizzled)
  float* Pr = (float*)(ws + F8BYTES);                // 20*2*160*64 f32 = 1.6 MB
  float* gp = Pr + 20 * 2 * 160 * 64;                // 320*128 f32
  float* Slog = gp + 320 * 128;                      // 10240 f32
  float* wnum = Slog + NROW;                         // 10240 f32

  k_prep<<<960, 256, 0, stream>>>(feat, labels, f8, gp);
  dim3 grid(320, 20);
  k_gram<<<grid, 64, 0, stream>>>(f8, Pr);
  k_ws<<<2600, 256, 0, stream>>>(Pr, feat, gp, Slog, wnum);
  k_final<<<1, 512, 0, stream>>>(Slog, wnum, labels, out);
}

// Round 19
// 50.157 us; speedup vs baseline: 4.7122x; 1.0671x over previous
//
#include <hip/hip_runtime.h>
#include <hip/hip_fp8.h>

// NewSupConLoss: B=512, L=20, D=128. Full Gram N=10240, fused exp/rowsum.
// Round 19: R18 (fp8 e4m3 operands, 6400 single-wave gram units) with k_ws
// slimmed: the 4 same-class pairs per block fold gp ONCE into LDS (84MB of
// redundant per-pair gp reads -> 26MB). k_gram byte-identical to R18.

#define NB 512
#define NL 20
#define NROW (NB * NL)            // 10240
#define F8BYTES (NROW * 128)      // 1,310,720
#define SCALE 4.5398160f          // sqrt(log2(e)/0.07); dot feeds exp2 directly
#define TEMP_INV 14.285714285714286f

typedef float f32x4 __attribute__((ext_vector_type(4)));

static __device__ __forceinline__ unsigned char f2fp8(float x) {
  __hip_fp8_e4m3 q(x);
  return (unsigned char)q.__x;
}

static __device__ __forceinline__ float fexp2(float x) {
#if __has_builtin(__builtin_amdgcn_exp2f)
  return __builtin_amdgcn_exp2f(x);
#else
  return exp2f(x);
#endif
}

// Blocks [0,640): fp32 -> fp8 rows a=l*512+i, scaled, 8B-chunk XOR-swizzled.
// Blocks [640,960): gp[c][grp][d] partial g-sums (16 independent loads).
__global__ __launch_bounds__(256) void k_prep(const float* __restrict__ feat,
                                              const int* __restrict__ labels,
                                              unsigned char* __restrict__ f8,
                                              float* __restrict__ gp) {
  const int b = blockIdx.x;
  if (b < 640) {
    int t = b * 256 + threadIdx.x;   // [0, 163840)
    int q = t & 15;                  // 8-elem chunk within row
    int a = t >> 4;                  // row 0..10239
    int l = a >> 9;
    int i = a & 511;
    const float* src = feat + (size_t)i * (NL * 128) + l * 128 + q * 8;
    float4 v0 = *(const float4*)src;
    float4 v1 = *(const float4*)(src + 4);
    unsigned long long u = 0;
    u |= (unsigned long long)f2fp8(v0.x * SCALE);
    u |= (unsigned long long)f2fp8(v0.y * SCALE) << 8;
    u |= (unsigned long long)f2fp8(v0.z * SCALE) << 16;
    u |= (unsigned long long)f2fp8(v0.w * SCALE) << 24;
    u |= (unsigned long long)f2fp8(v1.x * SCALE) << 32;
    u |= (unsigned long long)f2fp8(v1.y * SCALE) << 40;
    u |= (unsigned long long)f2fp8(v1.z * SCALE) << 48;
    u |= (unsigned long long)f2fp8(v1.w * SCALE) << 56;
    *(unsigned long long*)(f8 + (size_t)a * 128 + ((q ^ (a & 7)) << 3)) = u;
  } else {
    __shared__ float part[2][128];
    const int idx = b - 640;           // [0,320)
    const int c = idx >> 4, grp = idx & 15;
    const int d = threadIdx.x & 127, half = threadIdx.x >> 7;
    const int i0 = grp * 32 + half * 16;
    float s = 0.f;
#pragma unroll
    for (int k = 0; k < 16; ++k) {     // independent load pairs, latency-hidden
      int i = i0 + k;
      s += (float)labels[i * NL + c] * feat[(size_t)i * (NL * 128) + c * 128 + d];
    }
    part[half][d] = s;
    __syncthreads();
    if (half == 0) gp[(c * 16 + grp) * 128 + d] = part[0][d] + part[1][d];
  }
}

// Pr[c][h][sr][r] : partial row-sums of exp over 256 cols (class c, half h).
// Grid (320 = sr*2+h, 20 c), 64 threads (1 wave). Depth-1, 2x2KB LDS.
__global__ __launch_bounds__(64) void k_gram(const unsigned char* __restrict__ f8,
                                             float* __restrict__ Pr) {
  __shared__ unsigned char lds[4096];    // two wave-private 2KB slice buffers
  const int x = blockIdx.x;              // [0,320)
  const int h = x & 1, sr = x >> 1;      // col half, 64-row strip [sr*64,+64)
  const int c = blockIdx.y;              // class: cols [c*512 + h*256, +256)
  const int lane = threadIdx.x;          // 0..63
  const int fr = lane & 15, kg = lane >> 4;
  const int x8 = (fr & 7) << 3;

  // ---- persistent A fragments: 16 x long = 32 VGPR ----
  long af[4][4];   // [kk][m]
#pragma unroll
  for (int kk = 0; kk < 4; ++kk)
#pragma unroll
    for (int m = 0; m < 4; ++m)
      af[kk][m] = *(const long*)(f8 + (size_t)(sr * 64 + m * 16 + fr) * 128 +
                                 ((kk * 32 + kg * 8) ^ x8));

  const unsigned char* gB = f8 + ((size_t)c * 512 + h * 256) * 128 + lane * 16;
  auto stage = [&](int buf, int t) {     // slice t: 16 Gram-cols = 2KB
    const unsigned char* g = gB + t * 2048;
    unsigned char* lb = lds + buf * 2048 + lane * 16;
    __builtin_amdgcn_global_load_lds(
        (const __attribute__((address_space(1))) unsigned int*)g,
        (__attribute__((address_space(3))) unsigned int*)lb, 16, 0, 0);
    __builtin_amdgcn_global_load_lds(
        (const __attribute__((address_space(1))) unsigned int*)(g + 1024),
        (__attribute__((address_space(3))) unsigned int*)(lb + 1024), 16, 0, 0);
  };

  stage(0, 0);
  float esum[4][4] = {};   // [m][reg]

  // diag (i==j) lives in half (d8>>2), slices [td0, td0+4), d8 = sr&7
  const int d8 = sr & 7;
  const bool diagh = ((d8 >> 2) == h);
  const int td0 = (d8 & 3) * 4;

  for (int t = 0; t < 16; ++t) {
    asm volatile("" ::: "memory");   // keep stage below prior ds_reads
    if (t < 15) {
      stage((t + 1) & 1, t + 1);
      asm volatile("s_waitcnt vmcnt(2)" ::: "memory");   // slice t resident
    } else {
      asm volatile("s_waitcnt vmcnt(0)" ::: "memory");
    }

    const unsigned char* lb = lds + (t & 1) * 2048;
    f32x4 acc[4] = {};   // 64 rows x 16 cols
#pragma unroll
    for (int kk = 0; kk < 4; ++kk) {
      long bf = *(const long*)(lb + fr * 128 + ((kk * 32 + kg * 8) ^ x8));
#pragma unroll
      for (int m = 0; m < 4; ++m)
        acc[m] = __builtin_amdgcn_mfma_f32_16x16x32_fp8_fp8(af[kk][m], bf, acc[m], 0, 0, 0);
    }

    // ---- epilogue: exp + accumulate; mask only on the 4 diag slices ----
    if (diagh && t >= td0 && t < td0 + 4) {
      const int mt = t - td0;
#pragma unroll
      for (int m = 0; m < 4; ++m)
#pragma unroll
        for (int reg = 0; reg < 4; ++reg) {
          float ex = fexp2(acc[m][reg]);
          if (m == mt && (kg * 4 + reg) == fr) ex = 0.f;
          esum[m][reg] += ex;
        }
    } else {
#pragma unroll
      for (int m = 0; m < 4; ++m)
#pragma unroll
        for (int reg = 0; reg < 4; ++reg)
          esum[m][reg] += fexp2(acc[m][reg]);
    }
  }

  // ---- flush once: reduce over fr (16 cols) + plain stores ----
#pragma unroll
  for (int m = 0; m < 4; ++m)
#pragma unroll
    for (int reg = 0; reg < 4; ++reg) {
      float e = esum[m][reg];
      e += __shfl_xor(e, 1, 64); e += __shfl_xor(e, 2, 64);
      e += __shfl_xor(e, 4, 64); e += __shfl_xor(e, 8, 64);
      if (fr == 0)
        Pr[(((size_t)c * 2 + h) * 160 + sr) * 64 + m * 16 + kg * 4 + reg] = e;
    }
}

// Blocks [0,2560): wnum. The block's 4 pairs share class c = b/128: fold
// gp[c] once into LDS (2048 loads -> g[128]), then wave-per-pair dot.
// Blocks [2560,2600): Slog = log(sum of 40 Pr partials), coalesced.
__global__ __launch_bounds__(256) void k_ws(const float* __restrict__ Pr,
                                            const float* __restrict__ feat,
                                            const float* __restrict__ gp,
                                            float* __restrict__ Slog,
                                            float* __restrict__ wnum) {
  const int b = blockIdx.x;
  if (b < 2560) {
    __shared__ float part[2][128];
    __shared__ float gsh[128];
    const int tid = threadIdx.x;
    const int c = (b * 4) >> 9;                 // same class for all 4 pairs
    const int d = tid & 127, qh = tid >> 7;     // qh in {0,1}
    float s = 0.f;
#pragma unroll
    for (int q = 0; q < 8; ++q)
      s += gp[(c * 16 + qh * 8 + q) * 128 + d];
    part[qh][d] = s;
    __syncthreads();
    if (tid < 128) gsh[tid] = part[0][tid] + part[1][tid];
    __syncthreads();

    const int lane = tid & 63;
    const int p = b * 4 + (tid >> 6);           // pair c*512+i
    const int i = p & 511;
    float2 f = *(const float2*)(feat + (size_t)i * (NL * 128) + c * 128 + lane * 2);
    float2 gv = *(const float2*)(gsh + lane * 2);
    float v = f.x * gv.x + f.y * gv.y;
#pragma unroll
    for (int sh = 1; sh < 64; sh <<= 1) v += __shfl_xor(v, sh, 64);
    if (lane == 0) wnum[p] = (v - 1.f) * TEMP_INV;   // self term f.f==1 removed
  } else {
    int idx = (b - 2560) * 256 + threadIdx.x;   // [0, 10240)
    int c = idx >> 9, i = idx & 511;
    float s = 0.f;
#pragma unroll
    for (int l2 = 0; l2 < NL; ++l2) {
      const float* p2 = Pr + (((size_t)c * 2) * 160 + l2 * 8 + (i >> 6)) * 64 + (i & 63);
      s += p2[0] + p2[160 * 64];
    }
    Slog[idx] = logf(s);
  }
}

// Per-anchor combine + mean. One block, 512 threads.
__global__ __launch_bounds__(512) void k_final(const float* __restrict__ Slog,
                                               const float* __restrict__ wnum,
                                               const int* __restrict__ labels,
                                               float* __restrict__ out) {
  __shared__ float cnt[NL];
  __shared__ float red[8];
  const int i = threadIdx.x;
  if (i < NL) cnt[i] = 0.f;
  __syncthreads();
  int lab[NL];
#pragma unroll
  for (int cI = 0; cI < NL; ++cI) lab[cI] = labels[i * NL + cI];
#pragma unroll
  for (int cI = 0; cI < NL; ++cI)
    if (lab[cI]) atomicAdd(&cnt[cI], 1.f);
  __syncthreads();
  float avg = 0.f, acc = 0.f;
#pragma unroll
  for (int cI = 0; cI < NL; ++cI) {
    if (lab[cI]) {
      float wgt = cnt[cI] - 1.f;
      avg += wgt;
      acc += wnum[cI * NB + i] - wgt * Slog[cI * NB + i];
    }
  }
  float v = acc / (avg == 0.f ? 1.f : avg);
#pragma unroll
  for (int s = 1; s < 64; s <<= 1) v += __shfl_xor(v, s, 64);
  if ((i & 63) == 0) red[i >> 6] = v;
  __syncthreads();
  if (i == 0) {
    float tot = 0.f;
#pragma unroll
    for (int k = 0; k < 8; ++k) tot += red[k];
    out[0] = -(tot / (float)NB);
  }
}

extern "C" void kernel_launch(void* const* d_in, const int* in_sizes, int n_in,
                              void* d_out, int out_size, void* d_ws, size_t ws_size,
                              hipStream_t stream) {
  const float* feat = (const float*)d_in[0];
  const int* labels = (const int*)d_in[1];
  float* out = (float*)d_out;
  unsigned char* ws = (unsigned char*)d_ws;
  unsigned char* f8 = ws;                            // 1,310,720 B (fp8 swizzled)
  float* Pr = (float*)(ws + F8BYTES);                // 20*2*160*64 f32 = 1.6 MB
  float* gp = Pr + 20 * 2 * 160 * 64;                // 320*128 f32
  float* Slog = gp + 320 * 128;                      // 10240 f32
  float* wnum = Slog + NROW;                         // 10240 f32

  k_prep<<<960, 256, 0, stream>>>(feat, labels, f8, gp);
  dim3 grid(320, 20);
  k_gram<<<grid, 64, 0, stream>>>(f8, Pr);
  k_ws<<<2600, 256, 0, stream>>>(Pr, feat, gp, Slog, wnum);
  k_final<<<1, 512, 0, stream>>>(Slog, wnum, labels, out);
}